// Round 1
// baseline (1035.415 us; speedup 1.0000x reference)
//
#include <hip/hip_runtime.h>
#include <math.h>

#define CH_IN   512
#define CH_OUT  256
#define HWD     4096
#define BATCH   32
#define MAXSLOT 32   // ptr can never exceed 32: at most one append per batch step

// ---------------------------------------------------------------------------
// Kernel 1: proj[b,o,l] = sum_c W[o,c]*feats[b,c,l] + bias[o]
//           written to out[b, 0:256, :]; fused pooled partial sums
//           pooled_sum[b,o] += sum_l proj[b,o,l]*preds[b,l]   (scaled later)
// 128x128 tile, BK=16, 256 threads, 8x8 per-thread register block.
// ---------------------------------------------------------------------------
__global__ __launch_bounds__(256, 4) void k1_proj_gemm(
    const float* __restrict__ feats, const float* __restrict__ preds,
    const float* __restrict__ W, const float* __restrict__ bias,
    float* __restrict__ out, float* __restrict__ pooled)
{
    __shared__ float Ast[16][132];   // A^T tile: Ast[k][o]  (pitch 132 -> no conflicts)
    __shared__ float Bs [16][132];   // B tile:   Bs[k][l]

    const int t  = threadIdx.x;
    const int lt = blockIdx.x, ot = blockIdx.y, b = blockIdx.z;
    const int l0 = lt * 128, o0 = ot * 128;
    const int tx = t & 15, ty = t >> 4;

    float acc[8][8];
    #pragma unroll
    for (int i = 0; i < 8; i++)
        #pragma unroll
        for (int j = 0; j < 8; j++) acc[i][j] = 0.f;

    const float* Wb = W + (size_t)o0 * CH_IN;
    const float* Fb = feats + (size_t)b * CH_IN * HWD + l0;

    for (int k0 = 0; k0 < CH_IN; k0 += 16) {
        // stage A (W tile) transposed: 128 o x 16 k
        #pragma unroll
        for (int q = 0; q < 2; q++) {
            int idx = t + 256 * q;
            int r = idx >> 2, c4 = idx & 3;
            float4 v = *(const float4*)(Wb + (size_t)r * CH_IN + k0 + c4 * 4);
            Ast[c4 * 4 + 0][r] = v.x; Ast[c4 * 4 + 1][r] = v.y;
            Ast[c4 * 4 + 2][r] = v.z; Ast[c4 * 4 + 3][r] = v.w;
        }
        // stage B (feats tile): 16 k x 128 l
        #pragma unroll
        for (int q = 0; q < 2; q++) {
            int idx = t + 256 * q;
            int r = idx >> 5, c4 = idx & 31;
            *(float4*)&Bs[r][c4 * 4] =
                *(const float4*)(Fb + (size_t)(k0 + r) * HWD + c4 * 4);
        }
        __syncthreads();

        #pragma unroll
        for (int kk = 0; kk < 16; kk++) {
            float4 a0 = *(float4*)&Ast[kk][ty * 8];
            float4 a1 = *(float4*)&Ast[kk][ty * 8 + 4];
            float4 b0 = *(float4*)&Bs[kk][tx * 4];
            float4 b1 = *(float4*)&Bs[kk][tx * 4 + 64];
            float av[8] = {a0.x, a0.y, a0.z, a0.w, a1.x, a1.y, a1.z, a1.w};
            float bv[8] = {b0.x, b0.y, b0.z, b0.w, b1.x, b1.y, b1.z, b1.w};
            #pragma unroll
            for (int i = 0; i < 8; i++)
                #pragma unroll
                for (int j = 0; j < 8; j++)
                    acc[i][j] = fmaf(av[i], bv[j], acc[i][j]);
        }
        __syncthreads();
    }

    // epilogue: bias, store, fused pooled partials
    const int lA = l0 + tx * 4;
    const int lB = lA + 64;
    float pl[8];
    #pragma unroll
    for (int j = 0; j < 4; j++) {
        pl[j]     = preds[(size_t)b * HWD + lA + j];
        pl[4 + j] = preds[(size_t)b * HWD + lB + j];
    }
    #pragma unroll
    for (int i = 0; i < 8; i++) {
        int o = o0 + ty * 8 + i;
        float bvv = bias[o];
        float4 s0, s1;
        s0.x = acc[i][0] + bvv; s0.y = acc[i][1] + bvv;
        s0.z = acc[i][2] + bvv; s0.w = acc[i][3] + bvv;
        s1.x = acc[i][4] + bvv; s1.y = acc[i][5] + bvv;
        s1.z = acc[i][6] + bvv; s1.w = acc[i][7] + bvv;
        float* op = out + ((size_t)b * 512 + o) * HWD;
        *(float4*)(op + lA) = s0;
        *(float4*)(op + lB) = s1;
        float psum = s0.x * pl[0] + s0.y * pl[1] + s0.z * pl[2] + s0.w * pl[3]
                   + s1.x * pl[4] + s1.y * pl[5] + s1.z * pl[6] + s1.w * pl[7];
        // reduce across the 16 tx lanes (xor masks only touch tx bits)
        #pragma unroll
        for (int off = 1; off < 16; off <<= 1)
            psum += __shfl_xor(psum, off, 64);
        if (tx == 0) atomicAdd(&pooled[(size_t)b * CH_OUT + o], psum);
    }
}

// ---------------------------------------------------------------------------
// Kernel 2: sequential codebook update (one block; memory fits in LDS).
// ---------------------------------------------------------------------------
__global__ __launch_bounds__(256) void k2_mem_update(
    const float* __restrict__ pooled, const int* __restrict__ epoch_p,
    float* __restrict__ mem_out, int* __restrict__ ptr_out)
{
    __shared__ float mem[MAXSLOT][256];
    __shared__ float xs[256];
    __shared__ float norms2[MAXSLOT];
    __shared__ float sims[MAXSLOT];
    __shared__ float red[4];
    __shared__ float xnorm2_s;
    __shared__ int ptr_s, row_s, ema_s;

    const int t = threadIdx.x;
    const int lane = t & 63, wid = t >> 6;

    for (int r = 0; r < MAXSLOT; r++) mem[r][t] = 0.f;
    if (t < MAXSLOT) norms2[t] = 0.f;
    if (t == 0) ptr_s = 0;

    double thr_d = ((double)(*epoch_p)) / 10.0 - 2.0;
    thr_d = thr_d * 0.4 / 13.0 + 0.3;
    const float thr = (float)thr_d;
    __syncthreads();

    for (int bi = 0; bi < BATCH; bi++) {
        float x = pooled[(size_t)bi * 256 + t] * (1.0f / 4096.0f);
        xs[t] = x;
        float s = x * x;
        #pragma unroll
        for (int off = 32; off >= 1; off >>= 1) s += __shfl_xor(s, off, 64);
        if (lane == 0) red[wid] = s;
        __syncthreads();
        if (t == 0) xnorm2_s = red[0] + red[1] + red[2] + red[3];
        __syncthreads();

        const int P = ptr_s;
        const float xn = sqrtf(xnorm2_s);
        for (int p = wid; p < P; p += 4) {
            float d = mem[p][lane]       * xs[lane]
                    + mem[p][lane + 64]  * xs[lane + 64]
                    + mem[p][lane + 128] * xs[lane + 128]
                    + mem[p][lane + 192] * xs[lane + 192];
            #pragma unroll
            for (int off = 32; off >= 1; off >>= 1) d += __shfl_xor(d, off, 64);
            if (lane == 0) {
                float nrm = sqrtf(norms2[p]);
                if (nrm == 0.f) nrm = 1.f;
                sims[p] = d / (nrm * xn);
            }
        }
        __syncthreads();

        if (wid == 0) {
            float v = (lane < P) ? sims[lane] : -INFINITY;
            int idx = lane;
            #pragma unroll
            for (int off = 32; off >= 1; off >>= 1) {
                float ov = __shfl_down(v, off, 64);
                int   oi = __shfl_down(idx, off, 64);
                if (ov > v || (ov == v && oi < idx)) { v = ov; idx = oi; }
            }
            if (lane == 0) {
                int ema = (P > 0 && v >= thr) ? 1 : 0;
                ema_s = ema;
                row_s = ema ? idx : P;
                if (!ema) ptr_s = P + 1;
            }
        }
        __syncthreads();

        const int r = row_s;
        float nv = ema_s ? (mem[r][t] * 0.9f + 0.1f * xs[t]) : xs[t];
        mem[r][t] = nv;
        float s2 = nv * nv;
        #pragma unroll
        for (int off = 32; off >= 1; off >>= 1) s2 += __shfl_xor(s2, off, 64);
        if (lane == 0) red[wid] = s2;
        __syncthreads();
        if (t == 0) norms2[r] = red[0] + red[1] + red[2] + red[3];
        __syncthreads();
    }

    for (int r = 0; r < MAXSLOT; r++) mem_out[(size_t)r * 256 + t] = mem[r][t];
    if (t == 0) ptr_out[0] = ptr_s;
}

// ---------------------------------------------------------------------------
// Kernel 3: memory cross-attention. Per block: one batch b, 16 l-columns.
//  logits[p,l] = mem[p,:].proj[b,:,l] -> softmax over valid p -> aug = attn^T mem
// ---------------------------------------------------------------------------
#define BL 16
__global__ __launch_bounds__(256, 2) void k3_attention(
    const float* __restrict__ mem_g, const int* __restrict__ ptr_g,
    float* __restrict__ out)
{
    __shared__ float projLDS[256][BL + 4];   // [c][l]
    __shared__ float memLDS[MAXSLOT][260];   // [p][c]
    __shared__ float attnLDS[MAXSLOT][BL + 4];

    const int t = threadIdx.x;
    const int lt = blockIdx.x, b = blockIdx.y;
    const int l0 = lt * BL;
    const int P = ptr_g[0];

    // stage memory (32 x 256)
    #pragma unroll
    for (int q = 0; q < 8; q++) {
        int idx = t + 256 * q;
        int p = idx >> 6, c4 = idx & 63;
        *(float4*)&memLDS[p][c4 * 4] = *(const float4*)(mem_g + (size_t)p * 256 + c4 * 4);
    }
    // stage proj tile (256 c x BL l) from out[b, 0:256, l0:l0+BL]
    const float* projBase = out + (size_t)b * 512 * HWD + l0;
    #pragma unroll
    for (int q = 0; q < 4; q++) {
        int idx = t + 256 * q;
        int row = idx >> 2, c4 = idx & 3;
        *(float4*)&projLDS[row][c4 * 4] =
            *(const float4*)(projBase + (size_t)row * HWD + c4 * 4);
    }
    __syncthreads();

    // phase 1: logits
    {
        const int l = t & 15;
        const int pg = t >> 4;       // 16 groups x 2 slots
        const int pb = pg * 2;
        float a0 = 0.f, a1 = 0.f;
        for (int c = 0; c < 256; c++) {
            float pv = projLDS[c][l];
            a0 += memLDS[pb][c] * pv;
            a1 += memLDS[pb + 1][c] * pv;
        }
        if (pb < P)     attnLDS[pb][l]     = a0;
        if (pb + 1 < P) attnLDS[pb + 1][l] = a1;
    }
    __syncthreads();

    // phase 2: softmax over slots, per column
    if (t < BL) {
        float m = -INFINITY;
        for (int p = 0; p < P; p++) m = fmaxf(m, attnLDS[p][t]);
        float d = 0.f;
        for (int p = 0; p < P; p++) {
            float e = expf(attnLDS[p][t] - m);
            attnLDS[p][t] = e;
            d += e;
        }
        float inv = 1.f / d;
        for (int p = 0; p < P; p++) attnLDS[p][t] *= inv;
    }
    __syncthreads();

    // phase 3: aug[c,l] = sum_p attn[p,l]*mem[p,c]
    {
        const int l = t & 15;
        const int cg = t >> 4;
        float acc[16];
        #pragma unroll
        for (int k = 0; k < 16; k++) acc[k] = 0.f;
        for (int p = 0; p < P; p++) {
            float av = attnLDS[p][l];
            #pragma unroll
            for (int k = 0; k < 16; k++)
                acc[k] += memLDS[p][cg + 16 * k] * av;
        }
        float* augBase = out + ((size_t)b * 512 + 256) * HWD + l0;
        #pragma unroll
        for (int k = 0; k < 16; k++)
            augBase[(size_t)(cg + 16 * k) * HWD + l] = acc[k];
    }
}

// ---------------------------------------------------------------------------
extern "C" void kernel_launch(void* const* d_in, const int* in_sizes, int n_in,
                              void* d_out, int out_size, void* d_ws, size_t ws_size,
                              hipStream_t stream) {
    const float* feats = (const float*)d_in[0];
    const float* preds = (const float*)d_in[1];
    const float* W     = (const float*)d_in[2];
    const float* bias  = (const float*)d_in[3];
    const int*   epoch = (const int*)d_in[4];
    float* out = (float*)d_out;

    float* ws     = (float*)d_ws;
    float* pooled = ws;              // 32*256 floats (accumulated via atomics)
    float* mem_g  = ws + 8192;       // 32*256 floats
    int*   ptr_g  = (int*)(ws + 16384);

    hipMemsetAsync(pooled, 0, 8192 * sizeof(float), stream);

    k1_proj_gemm<<<dim3(32, 2, 32), 256, 0, stream>>>(feats, preds, W, bias, out, pooled);
    k2_mem_update<<<1, 256, 0, stream>>>(pooled, epoch, mem_g, ptr_g);
    k3_attention<<<dim3(HWD / BL, BATCH), 256, 0, stream>>>(mem_g, ptr_g, out);
}

// Round 2
// 724.698 us; speedup vs baseline: 1.4288x; 1.4288x over previous
//
#include <hip/hip_runtime.h>
#include <math.h>

#define CH_IN   512
#define CH_OUT  256
#define HWD     4096
#define BATCH   32
#define MAXSLOT 32   // ptr can never exceed 32: at most one append per batch step

typedef __attribute__((ext_vector_type(8))) short short8;
typedef __attribute__((ext_vector_type(4))) float floatx4;

// fp32 -> bf16 RNE, packed pair into one uint (low = a, high = b)
__device__ __forceinline__ unsigned int pk_bf16(float a, float b) {
    unsigned int ua = __float_as_uint(a);
    ua += 0x7fffu + ((ua >> 16) & 1u);
    unsigned int ub = __float_as_uint(b);
    ub += 0x7fffu + ((ub >> 16) & 1u);
    return (ua >> 16) | (ub & 0xffff0000u);
}

// ---------------------------------------------------------------------------
// Kernel 1: proj = W @ feats + b  via bf16 MFMA 16x16x32, fp32 accumulate.
// Block: 256 thr = 4 waves (2x2), tile 128o x 128l, BK=32.
// LDS: As[o][c] pitch 40 bf16 (b128 frag reads conflict-free),
//      Bs[l][c] pitch 42 bf16 (transpose writes 4-way, b32 frag reads free).
// Fused: pooled[b][o] += sum_l proj*preds (mean applied in k2).
// ---------------------------------------------------------------------------
#define PA 40
#define PB 42
__global__ __launch_bounds__(256) void k1_proj_gemm(
    const float* __restrict__ feats, const float* __restrict__ preds,
    const float* __restrict__ W, const float* __restrict__ bias,
    float* __restrict__ out, float* __restrict__ pooled)
{
    __shared__ __align__(16) unsigned short As[128 * PA];
    __shared__ __align__(16) unsigned short Bs[128 * PB];

    const int t  = threadIdx.x;
    const int lt = blockIdx.x, ot = blockIdx.y, b = blockIdx.z;
    const int l0 = lt * 128, o0 = ot * 128;
    const int lane = t & 63, wid = t >> 6;
    const int wm = wid & 1, wn = wid >> 1;       // wave 2x2 grid
    const int ln = lane & 15, quad = lane >> 4;

    floatx4 acc[4][4];
    #pragma unroll
    for (int i = 0; i < 4; i++)
        #pragma unroll
        for (int j = 0; j < 4; j++) acc[i][j] = (floatx4){0.f, 0.f, 0.f, 0.f};

    const float* Wb = W + (size_t)o0 * CH_IN;
    const float* Fb = feats + (size_t)b * CH_IN * HWD + l0;

    // B staging mapping: thread owns 4c x 4l micro-block
    const int l4 = t & 31;      // l = l4*4 + i
    const int cg = t >> 5;      // c = cg*4 + j

    for (int k0 = 0; k0 < CH_IN; k0 += 32) {
        // ---- stage A: W tile 128o x 32c ----
        #pragma unroll
        for (int q = 0; q < 4; q++) {
            int idx = t + 256 * q;
            int o = idx >> 3, c4 = idx & 7;
            float4 w = *(const float4*)(Wb + (size_t)o * CH_IN + k0 + c4 * 4);
            unsigned int u0 = pk_bf16(w.x, w.y);
            unsigned int u1 = pk_bf16(w.z, w.w);
            *(uint2*)(As + o * PA + c4 * 4) = make_uint2(u0, u1);
        }
        // ---- stage B: feats tile 32c x 128l, transposed to Bs[l][c] ----
        float4 f0 = *(const float4*)(Fb + (size_t)(k0 + cg * 4 + 0) * HWD + l4 * 4);
        float4 f1 = *(const float4*)(Fb + (size_t)(k0 + cg * 4 + 1) * HWD + l4 * 4);
        float4 f2 = *(const float4*)(Fb + (size_t)(k0 + cg * 4 + 2) * HWD + l4 * 4);
        float4 f3 = *(const float4*)(Fb + (size_t)(k0 + cg * 4 + 3) * HWD + l4 * 4);
        {
            const float v0[4] = {f0.x, f0.y, f0.z, f0.w};
            const float v1[4] = {f1.x, f1.y, f1.z, f1.w};
            const float v2[4] = {f2.x, f2.y, f2.z, f2.w};
            const float v3[4] = {f3.x, f3.y, f3.z, f3.w};
            #pragma unroll
            for (int i = 0; i < 4; i++) {
                unsigned short* row = Bs + (l4 * 4 + i) * PB + cg * 4;
                *(unsigned int*)(row)     = pk_bf16(v0[i], v1[i]);
                *(unsigned int*)(row + 2) = pk_bf16(v2[i], v3[i]);
            }
        }
        __syncthreads();

        // ---- fragments + MFMA ----
        short8 af[4], bf[4];
        #pragma unroll
        for (int mt = 0; mt < 4; mt++) {
            int row = wm * 64 + mt * 16 + ln;
            af[mt] = *(const short8*)(As + row * PA + quad * 8);
        }
        #pragma unroll
        for (int nt = 0; nt < 4; nt++) {
            int row = wn * 64 + nt * 16 + ln;
            const unsigned short* p = Bs + row * PB + quad * 8;
            union { short8 v; unsigned int u[4]; } r;
            r.u[0] = *(const unsigned int*)(p);
            r.u[1] = *(const unsigned int*)(p + 2);
            r.u[2] = *(const unsigned int*)(p + 4);
            r.u[3] = *(const unsigned int*)(p + 6);
            bf[nt] = r.v;
        }
        #pragma unroll
        for (int mt = 0; mt < 4; mt++)
            #pragma unroll
            for (int nt = 0; nt < 4; nt++)
                acc[mt][nt] = __builtin_amdgcn_mfma_f32_16x16x32_bf16(
                    af[mt], bf[nt], acc[mt][nt], 0, 0, 0);
        __syncthreads();
    }

    // ---- epilogue: bias add, store proj, fused pooled partials ----
    float pv[4];
    #pragma unroll
    for (int nt = 0; nt < 4; nt++)
        pv[nt] = preds[(size_t)b * HWD + l0 + wn * 64 + nt * 16 + ln];

    #pragma unroll
    for (int mt = 0; mt < 4; mt++) {
        #pragma unroll
        for (int r = 0; r < 4; r++) {
            int o = o0 + wm * 64 + mt * 16 + quad * 4 + r;
            float bv = bias[o];
            float* op = out + ((size_t)b * 512 + o) * HWD + l0 + wn * 64;
            float psum = 0.f;
            #pragma unroll
            for (int nt = 0; nt < 4; nt++) {
                float val = acc[mt][nt][r] + bv;
                op[nt * 16 + ln] = val;
                psum += val * pv[nt];
            }
            #pragma unroll
            for (int off = 1; off < 16; off <<= 1)
                psum += __shfl_xor(psum, off, 64);
            if (ln == 0)
                atomicAdd(&pooled[(size_t)b * CH_OUT + o], psum);
        }
    }
}

// ---------------------------------------------------------------------------
// Kernel 2: sequential codebook update (one block; memory fits in LDS).
// ---------------------------------------------------------------------------
__global__ __launch_bounds__(256) void k2_mem_update(
    const float* __restrict__ pooled, const int* __restrict__ epoch_p,
    float* __restrict__ mem_out, int* __restrict__ ptr_out)
{
    __shared__ float mem[MAXSLOT][256];
    __shared__ float xs[256];
    __shared__ float norms2[MAXSLOT];
    __shared__ float sims[MAXSLOT];
    __shared__ float red[4];
    __shared__ float xnorm2_s;
    __shared__ int ptr_s, row_s, ema_s;

    const int t = threadIdx.x;
    const int lane = t & 63, wid = t >> 6;

    for (int r = 0; r < MAXSLOT; r++) mem[r][t] = 0.f;
    if (t < MAXSLOT) norms2[t] = 0.f;
    if (t == 0) ptr_s = 0;

    double thr_d = ((double)(*epoch_p)) / 10.0 - 2.0;
    thr_d = thr_d * 0.4 / 13.0 + 0.3;
    const float thr = (float)thr_d;
    __syncthreads();

    for (int bi = 0; bi < BATCH; bi++) {
        float x = pooled[(size_t)bi * 256 + t] * (1.0f / 4096.0f);
        xs[t] = x;
        float s = x * x;
        #pragma unroll
        for (int off = 32; off >= 1; off >>= 1) s += __shfl_xor(s, off, 64);
        if (lane == 0) red[wid] = s;
        __syncthreads();
        if (t == 0) xnorm2_s = red[0] + red[1] + red[2] + red[3];
        __syncthreads();

        const int P = ptr_s;
        const float xn = sqrtf(xnorm2_s);
        for (int p = wid; p < P; p += 4) {
            float d = mem[p][lane]       * xs[lane]
                    + mem[p][lane + 64]  * xs[lane + 64]
                    + mem[p][lane + 128] * xs[lane + 128]
                    + mem[p][lane + 192] * xs[lane + 192];
            #pragma unroll
            for (int off = 32; off >= 1; off >>= 1) d += __shfl_xor(d, off, 64);
            if (lane == 0) {
                float nrm = sqrtf(norms2[p]);
                if (nrm == 0.f) nrm = 1.f;
                sims[p] = d / (nrm * xn);
            }
        }
        __syncthreads();

        if (wid == 0) {
            float v = (lane < P) ? sims[lane] : -INFINITY;
            int idx = lane;
            #pragma unroll
            for (int off = 32; off >= 1; off >>= 1) {
                float ov = __shfl_down(v, off, 64);
                int   oi = __shfl_down(idx, off, 64);
                if (ov > v || (ov == v && oi < idx)) { v = ov; idx = oi; }
            }
            if (lane == 0) {
                int ema = (P > 0 && v >= thr) ? 1 : 0;
                ema_s = ema;
                row_s = ema ? idx : P;
                if (!ema) ptr_s = P + 1;
            }
        }
        __syncthreads();

        const int r = row_s;
        float nv = ema_s ? (mem[r][t] * 0.9f + 0.1f * xs[t]) : xs[t];
        mem[r][t] = nv;
        float s2 = nv * nv;
        #pragma unroll
        for (int off = 32; off >= 1; off >>= 1) s2 += __shfl_xor(s2, off, 64);
        if (lane == 0) red[wid] = s2;
        __syncthreads();
        if (t == 0) norms2[r] = red[0] + red[1] + red[2] + red[3];
        __syncthreads();
    }

    for (int r = 0; r < MAXSLOT; r++) mem_out[(size_t)r * 256 + t] = mem[r][t];
    if (t == 0) ptr_out[0] = ptr_s;
}

// ---------------------------------------------------------------------------
// Kernel 3: memory cross-attention. Block = (b, 128 l-columns).
// Phase A: logits[32p][128l] from global proj + LDS mem (reg-blocked 2p x 8l)
// Phase B: softmax over slots per column (threads 0..127)
// Phase C: aug[c][l], thread owns one l + half of c; attn cached in regs.
// LDS ~50 KB -> 3 blocks/CU.
// ---------------------------------------------------------------------------
#define PM 260   // memLDS pitch (words); rows 16B-aligned
#define PT 132   // attnLDS pitch
__global__ __launch_bounds__(256) void k3_attention(
    const float* __restrict__ mem_g, const int* __restrict__ ptr_g,
    float* __restrict__ out)
{
    __shared__ __align__(16) float memL[MAXSLOT * PM];
    __shared__ float attnL[MAXSLOT * PT];

    const int t = threadIdx.x;
    const int lt = blockIdx.x, b = blockIdx.y;
    const int l0 = lt * 128;
    const int P = ptr_g[0];

    // stage memory 32 x 256
    #pragma unroll
    for (int q = 0; q < 8; q++) {
        int idx = t + 256 * q;
        int p = idx >> 6, c4 = idx & 63;
        *(float4*)(memL + p * PM + c4 * 4) =
            *(const float4*)(mem_g + (size_t)p * 256 + c4 * 4);
    }
    __syncthreads();

    // ---- phase A: logits, thread tile 2 slots x 8 l ----
    {
        const int tx = t & 15;        // l = tx*8 .. +7
        const int py = t >> 4;        // p0 = py*2
        const int p0 = py * 2;
        const float* projB = out + (size_t)b * 512 * HWD + l0 + tx * 8;
        float a0[8], a1[8];
        #pragma unroll
        for (int j = 0; j < 8; j++) { a0[j] = 0.f; a1[j] = 0.f; }
        const float* m0p = memL + p0 * PM;
        const float* m1p = memL + (p0 + 1) * PM;
        #pragma unroll 2
        for (int c = 0; c < 256; c++) {
            float4 pA = *(const float4*)(projB + (size_t)c * HWD);
            float4 pB = *(const float4*)(projB + (size_t)c * HWD + 4);
            float m0 = m0p[c], m1 = m1p[c];
            a0[0] = fmaf(m0, pA.x, a0[0]); a1[0] = fmaf(m1, pA.x, a1[0]);
            a0[1] = fmaf(m0, pA.y, a0[1]); a1[1] = fmaf(m1, pA.y, a1[1]);
            a0[2] = fmaf(m0, pA.z, a0[2]); a1[2] = fmaf(m1, pA.z, a1[2]);
            a0[3] = fmaf(m0, pA.w, a0[3]); a1[3] = fmaf(m1, pA.w, a1[3]);
            a0[4] = fmaf(m0, pB.x, a0[4]); a1[4] = fmaf(m1, pB.x, a1[4]);
            a0[5] = fmaf(m0, pB.y, a0[5]); a1[5] = fmaf(m1, pB.y, a1[5]);
            a0[6] = fmaf(m0, pB.z, a0[6]); a1[6] = fmaf(m1, pB.z, a1[6]);
            a0[7] = fmaf(m0, pB.w, a0[7]); a1[7] = fmaf(m1, pB.w, a1[7]);
        }
        #pragma unroll
        for (int j = 0; j < 8; j++) {
            attnL[p0 * PT + tx * 8 + j]       = a0[j];
            attnL[(p0 + 1) * PT + tx * 8 + j] = a1[j];
        }
    }
    __syncthreads();

    // ---- phase B: softmax over valid slots, per column ----
    if (t < 128) {
        float m = -INFINITY;
        for (int p = 0; p < P; p++) m = fmaxf(m, attnL[p * PT + t]);
        float d = 0.f;
        for (int p = 0; p < P; p++) {
            float e = __expf(attnL[p * PT + t] - m);
            attnL[p * PT + t] = e;
            d += e;
        }
        float inv = 1.f / d;
        for (int p = 0; p < P; p++) attnL[p * PT + t] *= inv;
    }
    __syncthreads();

    // ---- phase C: aug[c][l] = sum_p attn[p][l]*mem[p][c] ----
    {
        const int lC = t & 127;
        const int h = t >> 7;         // c half
        const int c0 = h * 128;
        float ar[MAXSLOT];
        for (int p = 0; p < P; p++) ar[p] = attnL[p * PT + lC];

        float* augB = out + ((size_t)b * 512 + 256 + c0) * HWD + l0 + lC;
        for (int cc = 0; cc < 128; cc += 8) {
            float acc[8];
            #pragma unroll
            for (int j = 0; j < 8; j++) acc[j] = 0.f;
            for (int p = 0; p < P; p++) {
                float4 mA = *(const float4*)(memL + p * PM + c0 + cc);
                float4 mB = *(const float4*)(memL + p * PM + c0 + cc + 4);
                float a = ar[p];
                acc[0] = fmaf(a, mA.x, acc[0]);
                acc[1] = fmaf(a, mA.y, acc[1]);
                acc[2] = fmaf(a, mA.z, acc[2]);
                acc[3] = fmaf(a, mA.w, acc[3]);
                acc[4] = fmaf(a, mB.x, acc[4]);
                acc[5] = fmaf(a, mB.y, acc[5]);
                acc[6] = fmaf(a, mB.z, acc[6]);
                acc[7] = fmaf(a, mB.w, acc[7]);
            }
            #pragma unroll
            for (int j = 0; j < 8; j++)
                augB[(size_t)(cc + j) * HWD] = acc[j];
        }
    }
}

// ---------------------------------------------------------------------------
extern "C" void kernel_launch(void* const* d_in, const int* in_sizes, int n_in,
                              void* d_out, int out_size, void* d_ws, size_t ws_size,
                              hipStream_t stream) {
    const float* feats = (const float*)d_in[0];
    const float* preds = (const float*)d_in[1];
    const float* W     = (const float*)d_in[2];
    const float* bias  = (const float*)d_in[3];
    const int*   epoch = (const int*)d_in[4];
    float* out = (float*)d_out;

    float* ws     = (float*)d_ws;
    float* pooled = ws;              // 32*256 floats (accumulated via atomics)
    float* mem_g  = ws + 8192;       // 32*256 floats
    int*   ptr_g  = (int*)(ws + 16384);

    hipMemsetAsync(pooled, 0, 8192 * sizeof(float), stream);

    k1_proj_gemm<<<dim3(32, 2, 32), 256, 0, stream>>>(feats, preds, W, bias, out, pooled);
    k2_mem_update<<<1, 256, 0, stream>>>(pooled, epoch, mem_g, ptr_g);
    k3_attention<<<dim3(32, 32), 256, 0, stream>>>(mem_g, ptr_g, out);
}